// Round 4
// baseline (693.026 us; speedup 1.0000x reference)
//
#include <hip/hip_runtime.h>
#include <hip/hip_bf16.h>
#include <cstdint>

// Problem constants (fixed by the reference)
#define NB 4
#define NH 128
#define NW 128
#define NC 256
#define NFF 1024
#define NE 4
#define NPATCH 4096   // B * 32 * 32
#define PPB 4         // patches per ffn block
#define BM 64         // token rows per ffn block (PPB*16)
#define FFC 256       // FF chunk streamed through LDS
#define NCHUNK (NFF / FFC)   // 4

typedef __attribute__((ext_vector_type(8))) short short8;
typedef __attribute__((ext_vector_type(8))) unsigned short ushort8;
typedef __attribute__((ext_vector_type(4))) float f32x4;

__device__ __forceinline__ unsigned short f2b(float f) {
  union { float f; uint32_t u; } v; v.f = f;
  uint32_t u = v.u + 0x7FFFu + ((v.u >> 16) & 1u);   // RNE
  return (unsigned short)(u >> 16);
}

// tanh-form GELU via sigmoid: x * sigmoid(1.5957691(x + 0.044715 x^3))
__device__ __forceinline__ float gelu_f(float v) {
  float u = v * v;
  float t = __builtin_fmaf(u, 0.044715f, 1.0f) * v;
  float e = __builtin_amdgcn_exp2f(t * -2.3022083f);   // exp(-1.59577*t)
  return v * __builtin_amdgcn_rcpf(1.0f + e);
}

// barrier that drains LDS ops only (no vmcnt drain -> global loads stay in flight)
__device__ __forceinline__ void bar_lgkm() {
  asm volatile("s_waitcnt lgkmcnt(0)" ::: "memory");
  __builtin_amdgcn_s_barrier();
}

// ---------------- weight fp32 -> bf16 (+ cnt zeroing) ----------------
__global__ __launch_bounds__(256) void convert_kernel(
    const float* __restrict__ W1, const float* __restrict__ W2,
    unsigned short* __restrict__ W1b, unsigned short* __restrict__ W2b,
    int* __restrict__ cnt, int n) {
  int i = blockIdx.x * blockDim.x + threadIdx.x;
  if (i < 2 * NE) cnt[i] = 0;
  if (i < n) {
    W1b[i] = f2b(W1[i]);
    W2b[i] = f2b(W2[i]);
  }
}

// ---------------- router: means -> logits -> softmax -> top2 -> lists ----------------
__global__ __launch_bounds__(256) void router_kernel(
    const float* __restrict__ x, const float* __restrict__ Wg,
    int* __restrict__ cnt, int* __restrict__ plist, float* __restrict__ wlist) {
  int p = blockIdx.x;                 // 0..4095
  int b = p >> 10, pi = p & 1023;
  int phi = pi >> 5, pwi = pi & 31;
  int c = threadIdx.x;                // 0..255 = channel

  const float* base = x + (((size_t)(b * NH + phi * 4) * NW) + pwi * 4) * NC + c;
  float s = 0.f;
#pragma unroll
  for (int i = 0; i < 4; i++)
#pragma unroll
    for (int j = 0; j < 4; j++)
      s += base[(i * NW + j) * NC];
  float mean = s * (1.f / 16.f);

  __shared__ float m_lds[NC];
  __shared__ double logit_lds[NE];
  m_lds[c] = mean;
  __syncthreads();

  int wid = c >> 6, lane = c & 63;    // wave w computes logit for expert w
  {
    const float* wg = Wg + wid * NC;
    double acc = 0.0;
#pragma unroll
    for (int q = 0; q < 4; q++)
      acc += (double)m_lds[lane + q * 64] * (double)wg[lane + q * 64];
    for (int off = 32; off; off >>= 1) acc += __shfl_down(acc, off);
    if (lane == 0) logit_lds[wid] = acc;
  }
  __syncthreads();

  if (c == 0) {
    double l[NE], pp[NE];
    double mx = -1e300;
#pragma unroll
    for (int i = 0; i < NE; i++) { l[i] = logit_lds[i]; mx = fmax(mx, l[i]); }
    double sum = 0.0;
#pragma unroll
    for (int i = 0; i < NE; i++) { pp[i] = exp(l[i] - mx); sum += pp[i]; }
#pragma unroll
    for (int i = 0; i < NE; i++) pp[i] /= sum;
    // top-2, ties -> lower index (lax.top_k semantics)
    int i1 = 0; double p1 = pp[0];
    for (int i = 1; i < NE; i++) if (pp[i] > p1) { p1 = pp[i]; i1 = i; }
    int i2 = -1; double p2 = -1.0;
    for (int i = 0; i < NE; i++) {
      if (i == i1) continue;
      if (pp[i] > p2) { p2 = pp[i]; i2 = i; }
    }
    double den = p1 + p2 + 1e-9;
    float w1 = (float)(p1 / den), w2 = (float)(p2 / den);
    int pos0 = atomicAdd(&cnt[0 * NE + i1], 1);
    plist[(0 * NE + i1) * NPATCH + pos0] = p;
    wlist[(0 * NE + i1) * NPATCH + pos0] = w1;
    int pos1 = atomicAdd(&cnt[1 * NE + i2], 1);
    plist[(1 * NE + i2) * NPATCH + pos1] = p;
    wlist[(1 * NE + i2) * NPATCH + pos1] = w2;
  }
}

// ---------------- expert FFN (fused GEMM1 -> gelu -> GEMM2) ----------------
// Block: 4 patches (64 token rows) of one (slot, expert) list.
// GEMM1 (swapped, H^T = W1 * X^T): wave w owns f-strip [w*64, w*64+64) of
//   each 256-wide FF chunk; every X fragment feeds 4 MFMAs, every W1 frag 4.
// GEMM2 (Y = H * W2^T): waves tile output 2x2 -> tok-strip 32 x c-strip 128;
//   every H fragment feeds 8 MFMAs, every W2 frag 2.
// LDS bytes/KFLOP ~ 1000/64 + 1000/128 + ~3 = ~26 (was ~27+27).
// Barriers are lgkm-only; bid&7 = e*2+slot -> XCD L2 affinity for weights.
__global__ __launch_bounds__(256, 2) void ffn_kernel(
    const float* __restrict__ x, const float* __restrict__ b1,
    const float* __restrict__ b2, const unsigned short* __restrict__ W1b,
    const unsigned short* __restrict__ W2b, const int* __restrict__ cnt,
    const int* __restrict__ plist, const float* __restrict__ wlist,
    float* __restrict__ out0, float* __restrict__ out1, int mode) {
  __shared__ unsigned short Xl[BM * NC];    // 32 KiB, swizzled, row stride 512B
  __shared__ unsigned short Hl[BM * FFC];   // 32 KiB, swizzled, row stride 512B

  int bid = blockIdx.x;
  int grp = bid & 7;                // -> XCD
  int e = grp >> 1, slot = grp & 1;
  int tile = bid >> 3;
  int le = slot * NE + e;
  int n = cnt[le];
  if (tile * PPB >= n) return;

  int tid = threadIdx.x, lane = tid & 63, wid = tid >> 6;
  int l15 = lane & 15;
  int kgrp = (lane >> 4) * 8;

  const int*   pl = plist + le * NPATCH + tile * PPB;
  const float* wl = wlist + le * NPATCH + tile * PPB;

  // ---- gather tokens -> bf16 LDS (swizzled, 16B writes) ----
  {
    int r  = tid >> 2;            // 0..63 token row; r>>4 == wid
    int c0 = (tid & 3) * 64;      // 64 channels per thread
    int pid = (tile * PPB + wid < n) ? pl[wid] : -1;
    int t = r & 15;
    if (pid >= 0) {
      int b = pid >> 10, pi = pid & 1023;
      int phi = pi >> 5, pwi = pi & 31;
      const float* src =
          x + (((size_t)(b * NH + phi * 4 + (t >> 2)) * NW) + pwi * 4 + (t & 3)) * NC + c0;
#pragma unroll
      for (int q = 0; q < 8; q++) {
        float4 v0 = *reinterpret_cast<const float4*>(src + q * 8);
        float4 v1 = *reinterpret_cast<const float4*>(src + q * 8 + 4);
        ushort8 h;
        h[0] = f2b(v0.x); h[1] = f2b(v0.y); h[2] = f2b(v0.z); h[3] = f2b(v0.w);
        h[4] = f2b(v1.x); h[5] = f2b(v1.y); h[6] = f2b(v1.z); h[7] = f2b(v1.w);
        int boff = (r * 512 + (c0 + q * 8) * 2) ^ ((r & 7) << 4);
        *reinterpret_cast<ushort8*>((char*)Xl + boff) = h;
      }
    } else {
      ushort8 h = (ushort8)0;
#pragma unroll
      for (int q = 0; q < 8; q++) {
        int boff = (r * 512 + (c0 + q * 8) * 2) ^ ((r & 7) << 4);
        *reinterpret_cast<ushort8*>((char*)Xl + boff) = h;
      }
    }
  }
  bar_lgkm();

  int wr = wid & 1, wc = wid >> 1;   // GEMM2 output tile: tok half, c quarter... (c half of 256 = 128)

  f32x4 acc2[8][2];   // [ct][rt] : Y[wr*32 + rt*16.., wc*128 + ct*16..]
#pragma unroll
  for (int a = 0; a < 8; a++)
#pragma unroll
    for (int b = 0; b < 2; b++)
#pragma unroll
      for (int j = 0; j < 4; j++) acc2[a][b][j] = 0.f;

  const unsigned short* W1e = W1b + (size_t)e * NFF * NC;
  const unsigned short* W2e = W2b + (size_t)e * NC * NFF;
  const float* b1e = b1 + e * NFF;
  const float* b2e = b2 + e * NC;

  for (int fc = 0; fc < NCHUNK; fc++) {
    // ---- GEMM1 (swapped): H^T[f, token] += W1[f,k] * X[token,k] ----
    f32x4 acc1[4][4];   // [ftl][nt]
#pragma unroll
    for (int a = 0; a < 4; a++)
#pragma unroll
      for (int b = 0; b < 4; b++)
#pragma unroll
        for (int j = 0; j < 4; j++) acc1[a][b][j] = 0.f;

#pragma unroll
    for (int ks = 0; ks < 8; ks++) {        // K = NC = 256
      int k = ks * 32 + kgrp;
      short8 bX[4];
#pragma unroll
      for (int nt = 0; nt < 4; nt++) {
        int row = nt * 16 + l15;
        int boff = (row * 512 + k * 2) ^ ((row & 7) << 4);
        bX[nt] = *reinterpret_cast<const short8*>((const char*)Xl + boff);
      }
#pragma unroll
      for (int ftl = 0; ftl < 4; ftl++) {
        int f = fc * FFC + wid * 64 + ftl * 16 + l15;
        short8 aW = *reinterpret_cast<const short8*>(W1e + (size_t)f * NC + k);
#pragma unroll
        for (int nt = 0; nt < 4; nt++)
          acc1[ftl][nt] = __builtin_amdgcn_mfma_f32_16x16x32_bf16(aW, bX[nt], acc1[ftl][nt], 0, 0, 0);
      }
    }

    bar_lgkm();   // all waves done reading Hl (previous chunk's GEMM2)

    // ---- bias + gelu -> bf16 Hl[token][f] ----
#pragma unroll
    for (int ftl = 0; ftl < 4; ftl++) {
      int f0 = wid * 64 + ftl * 16 + (lane >> 4) * 4;   // f within chunk
      float4 bv = *reinterpret_cast<const float4*>(b1e + fc * FFC + f0);
#pragma unroll
      for (int nt = 0; nt < 4; nt++) {
        int token = nt * 16 + l15;
        ushort4 hp;
        hp.x = f2b(gelu_f(acc1[ftl][nt][0] + bv.x));
        hp.y = f2b(gelu_f(acc1[ftl][nt][1] + bv.y));
        hp.z = f2b(gelu_f(acc1[ftl][nt][2] + bv.z));
        hp.w = f2b(gelu_f(acc1[ftl][nt][3] + bv.w));
        int boff = (token * 512 + f0 * 2) ^ ((token & 7) << 4);
        *reinterpret_cast<ushort4*>((char*)Hl + boff) = hp;
      }
    }
    bar_lgkm();   // Hl chunk visible to all waves

    // ---- GEMM2: Y[token, c] += H[token, f] * W2[c, f] ----
#pragma unroll
    for (int ks = 0; ks < 8; ks++) {        // K = FFC = 256
      int kf = ks * 32 + kgrp;
      short8 aH[2];
#pragma unroll
      for (int rt = 0; rt < 2; rt++) {
        int row = wr * 32 + rt * 16 + l15;
        int boff = (row * 512 + kf * 2) ^ ((row & 7) << 4);
        aH[rt] = *reinterpret_cast<const short8*>((const char*)Hl + boff);
      }
#pragma unroll
      for (int ct = 0; ct < 8; ct++) {
        int c = wc * 128 + ct * 16 + l15;
        short8 bW = *reinterpret_cast<const short8*>(W2e + (size_t)c * NFF + fc * FFC + kf);
#pragma unroll
        for (int rt = 0; rt < 2; rt++)
          acc2[ct][rt] = __builtin_amdgcn_mfma_f32_16x16x32_bf16(aH[rt], bW, acc2[ct][rt], 0, 0, 0);
      }
    }
  }

  // ---- epilogue: out_slot = w * (Y + b2) ----
  float* obase = (slot == 0) ? out0 : out1;
  float bias2[8];
#pragma unroll
  for (int ct = 0; ct < 8; ct++) bias2[ct] = b2e[wc * 128 + ct * 16 + l15];

#pragma unroll
  for (int rt = 0; rt < 2; rt++) {
    int pslot = wr * 2 + rt;                 // patch index within block
    if (tile * PPB + pslot >= n) continue;
    int pid = pl[pslot];
    float wgt = wl[pslot];
    int b = pid >> 10, pi = pid & 1023;
    int phi = pi >> 5, pwi = pi & 31;
#pragma unroll
    for (int i = 0; i < 4; i++) {
      int t = (lane >> 4) * 4 + i;   // token within patch
      float* dst =
          obase + (((size_t)(b * NH + phi * 4 + (t >> 2)) * NW) + pwi * 4 + (t & 3)) * NC;
#pragma unroll
      for (int ct = 0; ct < 8; ct++) {
        int c = wc * 128 + ct * 16 + l15;
        float val = wgt * (acc2[ct][rt][i] + bias2[ct]);
        if (mode == 0) dst[c] = val;
        else atomicAdd(&dst[c], val);
      }
    }
  }
}

// ---------------- combine: out += y1 ----------------
__global__ __launch_bounds__(256) void combine_kernel(
    float* __restrict__ out, const float* __restrict__ y1, int n4) {
  int i = blockIdx.x * blockDim.x + threadIdx.x;
  int stride = gridDim.x * blockDim.x;
  for (; i < n4; i += stride) {
    float4 a = reinterpret_cast<float4*>(out)[i];
    float4 b = reinterpret_cast<const float4*>(y1)[i];
    a.x += b.x; a.y += b.y; a.z += b.z; a.w += b.w;
    reinterpret_cast<float4*>(out)[i] = a;
  }
}

extern "C" void kernel_launch(void* const* d_in, const int* in_sizes, int n_in,
                              void* d_out, int out_size, void* d_ws, size_t ws_size,
                              hipStream_t stream) {
  const float* x  = (const float*)d_in[0];
  const float* Wg = (const float*)d_in[1];
  const float* W1 = (const float*)d_in[2];
  const float* b1 = (const float*)d_in[3];
  const float* W2 = (const float*)d_in[4];
  const float* b2 = (const float*)d_in[5];
  float* out = (float*)d_out;

  char* ws = (char*)d_ws;
  unsigned short* W1b = (unsigned short*)ws;                                  // 2 MiB
  unsigned short* W2b = (unsigned short*)(ws + (size_t)2 * 1024 * 1024);      // 2 MiB
  int*   cnt   = (int*)(ws + (size_t)4 * 1024 * 1024);                        // 8 ints
  int*   plist = (int*)(ws + (size_t)4 * 1024 * 1024 + 256);                  // 128 KiB
  float* wlist = (float*)(ws + (size_t)4 * 1024 * 1024 + 256 +
                          (size_t)2 * NE * NPATCH * sizeof(int));             // 128 KiB
  float* y1buf = (float*)(ws + (size_t)8 * 1024 * 1024);                      // 64 MiB

  size_t need = (size_t)8 * 1024 * 1024 + (size_t)NB * NH * NW * NC * sizeof(float);
  int mode = (ws_size >= need) ? 0 : 1;   // 0: slot buffers + combine, 1: atomic

  if (mode == 1)
    hipMemsetAsync(out, 0, (size_t)out_size * sizeof(float), stream);

  convert_kernel<<<dim3(4096), dim3(256), 0, stream>>>(W1, W2, W1b, W2b, cnt, NE * NFF * NC);
  router_kernel<<<dim3(NPATCH), dim3(256), 0, stream>>>(x, Wg, cnt, plist, wlist);

  float* out1 = (mode == 0) ? y1buf : out;
  ffn_kernel<<<dim3(8192), dim3(256), 0, stream>>>(
      x, b1, b2, W1b, W2b, cnt, plist, wlist, out, out1, mode);

  if (mode == 0) {
    int n4 = NB * NH * NW * NC / 4;
    combine_kernel<<<dim3(2048), dim3(256), 0, stream>>>(out, y1buf, n4);
  }
}

// Round 5
// 690.082 us; speedup vs baseline: 1.0043x; 1.0043x over previous
//
#include <hip/hip_runtime.h>
#include <hip/hip_bf16.h>
#include <cstdint>

// Problem constants (fixed by the reference)
#define NB 4
#define NH 128
#define NW 128
#define NC 256
#define NFF 1024
#define NE 4
#define NPATCH 4096   // B * 32 * 32
#define PPB 8         // patches per ffn block
#define BM 128        // token rows per ffn block (PPB*16)
#define FFC 256       // FF chunk streamed through LDS
#define NCHUNK (NFF / FFC)   // 4

typedef __attribute__((ext_vector_type(8))) short short8;
typedef __attribute__((ext_vector_type(8))) unsigned short ushort8;
typedef __attribute__((ext_vector_type(4))) float f32x4;

__device__ __forceinline__ unsigned short f2b(float f) {
  union { float f; uint32_t u; } v; v.f = f;
  uint32_t u = v.u + 0x7FFFu + ((v.u >> 16) & 1u);   // RNE
  return (unsigned short)(u >> 16);
}

// tanh-form GELU via sigmoid: x * sigmoid(1.5957691(x + 0.044715 x^3))
__device__ __forceinline__ float gelu_f(float v) {
  float u = v * v;
  float t = __builtin_fmaf(u, 0.044715f, 1.0f) * v;
  float e = __builtin_amdgcn_exp2f(t * -2.3022083f);   // exp(-1.59577*t)
  return v * __builtin_amdgcn_rcpf(1.0f + e);
}

// barrier that drains LDS ops only (no vmcnt drain -> global loads stay in flight)
__device__ __forceinline__ void bar_lgkm() {
  asm volatile("s_waitcnt lgkmcnt(0)" ::: "memory");
  __builtin_amdgcn_s_barrier();
}

// ---------------- weight fp32 -> bf16 (+ cnt zeroing) ----------------
__global__ __launch_bounds__(256) void convert_kernel(
    const float* __restrict__ W1, const float* __restrict__ W2,
    unsigned short* __restrict__ W1b, unsigned short* __restrict__ W2b,
    int* __restrict__ cnt, int n) {
  int i = blockIdx.x * blockDim.x + threadIdx.x;
  if (i < 2 * NE) cnt[i] = 0;
  if (i < n) {
    W1b[i] = f2b(W1[i]);
    W2b[i] = f2b(W2[i]);
  }
}

// ---------------- router: means -> logits -> softmax -> top2 -> lists ----------------
__global__ __launch_bounds__(256) void router_kernel(
    const float* __restrict__ x, const float* __restrict__ Wg,
    int* __restrict__ cnt, int* __restrict__ plist, float* __restrict__ wlist) {
  int p = blockIdx.x;                 // 0..4095
  int b = p >> 10, pi = p & 1023;
  int phi = pi >> 5, pwi = pi & 31;
  int c = threadIdx.x;                // 0..255 = channel

  const float* base = x + (((size_t)(b * NH + phi * 4) * NW) + pwi * 4) * NC + c;
  float s = 0.f;
#pragma unroll
  for (int i = 0; i < 4; i++)
#pragma unroll
    for (int j = 0; j < 4; j++)
      s += base[(i * NW + j) * NC];
  float mean = s * (1.f / 16.f);

  __shared__ float m_lds[NC];
  __shared__ double logit_lds[NE];
  m_lds[c] = mean;
  __syncthreads();

  int wid = c >> 6, lane = c & 63;    // wave w computes logit for expert w
  {
    const float* wg = Wg + wid * NC;
    double acc = 0.0;
#pragma unroll
    for (int q = 0; q < 4; q++)
      acc += (double)m_lds[lane + q * 64] * (double)wg[lane + q * 64];
    for (int off = 32; off; off >>= 1) acc += __shfl_down(acc, off);
    if (lane == 0) logit_lds[wid] = acc;
  }
  __syncthreads();

  if (c == 0) {
    double l[NE], pp[NE];
    double mx = -1e300;
#pragma unroll
    for (int i = 0; i < NE; i++) { l[i] = logit_lds[i]; mx = fmax(mx, l[i]); }
    double sum = 0.0;
#pragma unroll
    for (int i = 0; i < NE; i++) { pp[i] = exp(l[i] - mx); sum += pp[i]; }
#pragma unroll
    for (int i = 0; i < NE; i++) pp[i] /= sum;
    // top-2, ties -> lower index (lax.top_k semantics)
    int i1 = 0; double p1 = pp[0];
    for (int i = 1; i < NE; i++) if (pp[i] > p1) { p1 = pp[i]; i1 = i; }
    int i2 = -1; double p2 = -1.0;
    for (int i = 0; i < NE; i++) {
      if (i == i1) continue;
      if (pp[i] > p2) { p2 = pp[i]; i2 = i; }
    }
    double den = p1 + p2 + 1e-9;
    float w1 = (float)(p1 / den), w2 = (float)(p2 / den);
    int pos0 = atomicAdd(&cnt[0 * NE + i1], 1);
    plist[(0 * NE + i1) * NPATCH + pos0] = p;
    wlist[(0 * NE + i1) * NPATCH + pos0] = w1;
    int pos1 = atomicAdd(&cnt[1 * NE + i2], 1);
    plist[(1 * NE + i2) * NPATCH + pos1] = p;
    wlist[(1 * NE + i2) * NPATCH + pos1] = w2;
  }
}

// ---------------- expert FFN (fused GEMM1 -> gelu -> GEMM2) ----------------
// Block: 8 patches (128 token rows) of one (slot, expert) list; 512 thr, 8 waves.
// GEMM1 (swapped, H^T = W1 * X^T): waves tile 4(f) x 2(tok): f-strip 64
//   (ftl=4), tok-strip 64 (nt=4). X frags for ks0-3 hoisted to regs once
//   per block (fc-invariant); W1 loads software-pipelined 1 ks ahead.
// GEMM2 (Y = H * W2^T): waves tile 2(tok) x 4(c): tok-strip 64 (rt=4),
//   c-strip 64 (ct=4); W2 loads pipelined 1 ks ahead.
// Per-MFMA traffic: X-LDS ~128B, W1 256B, H-LDS 256B, W2 256B.
// Barriers are lgkm-only; bid&7 = e*2+slot -> XCD L2 affinity for weights.
__global__ __launch_bounds__(512, 2) void ffn_kernel(
    const float* __restrict__ x, const float* __restrict__ b1,
    const float* __restrict__ b2, const unsigned short* __restrict__ W1b,
    const unsigned short* __restrict__ W2b, const int* __restrict__ cnt,
    const int* __restrict__ plist, const float* __restrict__ wlist,
    float* __restrict__ out0, float* __restrict__ out1, int mode) {
  __shared__ unsigned short Xl[BM * NC];    // 64 KiB, swizzled, row stride 512B
  __shared__ unsigned short Hl[BM * FFC];   // 64 KiB, swizzled, row stride 512B

  int bid = blockIdx.x;
  int grp = bid & 7;                // -> XCD
  int e = grp >> 1, slot = grp & 1;
  int tile = bid >> 3;
  int le = slot * NE + e;
  int n = cnt[le];
  if (tile * PPB >= n) return;

  int tid = threadIdx.x, lane = tid & 63, wid = tid >> 6;
  int l15 = lane & 15;
  int kgrp = (lane >> 4) * 8;

  const int*   pl = plist + le * NPATCH + tile * PPB;
  const float* wl = wlist + le * NPATCH + tile * PPB;

  const unsigned short* W1e = W1b + (size_t)e * NFF * NC;
  const unsigned short* W2e = W2b + (size_t)e * NC * NFF;
  const float* b1e = b1 + e * NFF;
  const float* b2e = b2 + e * NC;

  // ---- gather tokens -> bf16 LDS (swizzled, 16B writes) ----
  {
    int r  = tid >> 2;            // 0..127 token row; r>>4 == wid
    int c0 = (tid & 3) * 64;      // 64 channels per thread
    int pid = (tile * PPB + wid < n) ? pl[wid] : -1;
    int t = r & 15;
    if (pid >= 0) {
      int b = pid >> 10, pi = pid & 1023;
      int phi = pi >> 5, pwi = pi & 31;
      const float* src =
          x + (((size_t)(b * NH + phi * 4 + (t >> 2)) * NW) + pwi * 4 + (t & 3)) * NC + c0;
#pragma unroll
      for (int q = 0; q < 8; q++) {
        float4 v0 = *reinterpret_cast<const float4*>(src + q * 8);
        float4 v1 = *reinterpret_cast<const float4*>(src + q * 8 + 4);
        ushort8 h;
        h[0] = f2b(v0.x); h[1] = f2b(v0.y); h[2] = f2b(v0.z); h[3] = f2b(v0.w);
        h[4] = f2b(v1.x); h[5] = f2b(v1.y); h[6] = f2b(v1.z); h[7] = f2b(v1.w);
        int boff = (r * 512 + (c0 + q * 8) * 2) ^ ((r & 7) << 4);
        *reinterpret_cast<ushort8*>((char*)Xl + boff) = h;
      }
    } else {
      ushort8 h = (ushort8)0;
#pragma unroll
      for (int q = 0; q < 8; q++) {
        int boff = (r * 512 + (c0 + q * 8) * 2) ^ ((r & 7) << 4);
        *reinterpret_cast<ushort8*>((char*)Xl + boff) = h;
      }
    }
  }
  bar_lgkm();

  // wave roles
  int wf = wid & 3, wt = wid >> 2;    // GEMM1: f-col (strip 64), tok-row (strip 64)
  int wt2 = wid & 1, wc = wid >> 1;   // GEMM2: tok-row (strip 64), c-col (strip 64)

  // ---- hoist X B-frags for ks=0..3 into registers (fc-invariant) ----
  short8 bXr[4][4];   // [ks][nt]
#pragma unroll
  for (int ks = 0; ks < 4; ks++) {
    int k = ks * 32 + kgrp;
#pragma unroll
    for (int nt = 0; nt < 4; nt++) {
      int row = wt * 64 + nt * 16 + l15;
      int boff = (row * 512 + k * 2) ^ ((row & 7) << 4);
      bXr[ks][nt] = *reinterpret_cast<const short8*>((const char*)Xl + boff);
    }
  }

  f32x4 acc2[4][4];   // [ct][rt] : Y[wt2*64 + rt*16.., wc*64 + ct*16..]
#pragma unroll
  for (int a = 0; a < 4; a++)
#pragma unroll
    for (int b = 0; b < 4; b++)
#pragma unroll
      for (int j = 0; j < 4; j++) acc2[a][b][j] = 0.f;

  for (int fc = 0; fc < NCHUNK; fc++) {
    // ---- GEMM1 (swapped): H^T[f, token] += W1[f,k] * X[token,k] ----
    f32x4 acc1[4][4];   // [ftl][nt]
#pragma unroll
    for (int a = 0; a < 4; a++)
#pragma unroll
      for (int b = 0; b < 4; b++)
#pragma unroll
        for (int j = 0; j < 4; j++) acc1[a][b][j] = 0.f;

    short8 aWp[2][4];   // W1 pipeline, 1 ks ahead
#pragma unroll
    for (int ftl = 0; ftl < 4; ftl++) {
      int f = fc * FFC + wf * 64 + ftl * 16 + l15;
      aWp[0][ftl] = *reinterpret_cast<const short8*>(W1e + (size_t)f * NC + kgrp);
    }
#pragma unroll
    for (int ks = 0; ks < 8; ks++) {        // K = NC = 256
      int cur = ks & 1;
      if (ks < 7) {
        int k2 = (ks + 1) * 32 + kgrp;
#pragma unroll
        for (int ftl = 0; ftl < 4; ftl++) {
          int f = fc * FFC + wf * 64 + ftl * 16 + l15;
          aWp[cur ^ 1][ftl] = *reinterpret_cast<const short8*>(W1e + (size_t)f * NC + k2);
        }
      }
      short8 bX[4];
      if (ks < 4) {
#pragma unroll
        for (int nt = 0; nt < 4; nt++) bX[nt] = bXr[ks][nt];
      } else {
        int k = ks * 32 + kgrp;
#pragma unroll
        for (int nt = 0; nt < 4; nt++) {
          int row = wt * 64 + nt * 16 + l15;
          int boff = (row * 512 + k * 2) ^ ((row & 7) << 4);
          bX[nt] = *reinterpret_cast<const short8*>((const char*)Xl + boff);
        }
      }
#pragma unroll
      for (int ftl = 0; ftl < 4; ftl++)
#pragma unroll
        for (int nt = 0; nt < 4; nt++)
          acc1[ftl][nt] = __builtin_amdgcn_mfma_f32_16x16x32_bf16(aWp[cur][ftl], bX[nt], acc1[ftl][nt], 0, 0, 0);
    }

    bar_lgkm();   // all waves done reading Hl (previous chunk's GEMM2)

    // ---- bias + gelu -> bf16 Hl[token][f] ----
#pragma unroll
    for (int ftl = 0; ftl < 4; ftl++) {
      int f0 = wf * 64 + ftl * 16 + (lane >> 4) * 4;   // f within chunk
      float4 bv = *reinterpret_cast<const float4*>(b1e + fc * FFC + f0);
#pragma unroll
      for (int nt = 0; nt < 4; nt++) {
        int token = wt * 64 + nt * 16 + l15;
        ushort4 hp;
        hp.x = f2b(gelu_f(acc1[ftl][nt][0] + bv.x));
        hp.y = f2b(gelu_f(acc1[ftl][nt][1] + bv.y));
        hp.z = f2b(gelu_f(acc1[ftl][nt][2] + bv.z));
        hp.w = f2b(gelu_f(acc1[ftl][nt][3] + bv.w));
        int boff = (token * 512 + f0 * 2) ^ ((token & 7) << 4);
        *reinterpret_cast<ushort4*>((char*)Hl + boff) = hp;
      }
    }
    bar_lgkm();   // Hl chunk visible to all waves

    // ---- GEMM2: Y[token, c] += H[token, f] * W2[c, f] ----
    short8 bWp[2][4];   // W2 pipeline, 1 ks ahead
#pragma unroll
    for (int ct = 0; ct < 4; ct++) {
      int c = wc * 64 + ct * 16 + l15;
      bWp[0][ct] = *reinterpret_cast<const short8*>(W2e + (size_t)c * NFF + fc * FFC + kgrp);
    }
#pragma unroll
    for (int ks = 0; ks < 8; ks++) {        // K = FFC = 256
      int cur = ks & 1;
      if (ks < 7) {
        int kf2 = (ks + 1) * 32 + kgrp;
#pragma unroll
        for (int ct = 0; ct < 4; ct++) {
          int c = wc * 64 + ct * 16 + l15;
          bWp[cur ^ 1][ct] = *reinterpret_cast<const short8*>(W2e + (size_t)c * NFF + fc * FFC + kf2);
        }
      }
      int kf = ks * 32 + kgrp;
      short8 aH[4];
#pragma unroll
      for (int rt = 0; rt < 4; rt++) {
        int row = wt2 * 64 + rt * 16 + l15;
        int boff = (row * 512 + kf * 2) ^ ((row & 7) << 4);
        aH[rt] = *reinterpret_cast<const short8*>((const char*)Hl + boff);
      }
#pragma unroll
      for (int ct = 0; ct < 4; ct++)
#pragma unroll
        for (int rt = 0; rt < 4; rt++)
          acc2[ct][rt] = __builtin_amdgcn_mfma_f32_16x16x32_bf16(aH[rt], bWp[cur][ct], acc2[ct][rt], 0, 0, 0);
    }
  }

  // ---- epilogue: out_slot = w * (Y + b2) ----
  float* obase = (slot == 0) ? out0 : out1;
  float bias2[4];
#pragma unroll
  for (int ct = 0; ct < 4; ct++) bias2[ct] = b2e[wc * 64 + ct * 16 + l15];

#pragma unroll
  for (int rt = 0; rt < 4; rt++) {
    int pslot = wt2 * 4 + rt;                // patch index within block
    if (tile * PPB + pslot >= n) continue;
    int pid = pl[pslot];
    float wgt = wl[pslot];
    int b = pid >> 10, pi = pid & 1023;
    int phi = pi >> 5, pwi = pi & 31;
#pragma unroll
    for (int i = 0; i < 4; i++) {
      int t = (lane >> 4) * 4 + i;   // token within patch
      float* dst =
          obase + (((size_t)(b * NH + phi * 4 + (t >> 2)) * NW) + pwi * 4 + (t & 3)) * NC;
#pragma unroll
      for (int ct = 0; ct < 4; ct++) {
        int c = wc * 64 + ct * 16 + l15;
        float val = wgt * (acc2[ct][rt][i] + bias2[ct]);
        if (mode == 0) dst[c] = val;
        else atomicAdd(&dst[c], val);
      }
    }
  }
}

// ---------------- combine: out += y1 ----------------
__global__ __launch_bounds__(256) void combine_kernel(
    float* __restrict__ out, const float* __restrict__ y1, int n4) {
  int i = blockIdx.x * blockDim.x + threadIdx.x;
  int stride = gridDim.x * blockDim.x;
  for (; i < n4; i += stride) {
    float4 a = reinterpret_cast<float4*>(out)[i];
    float4 b = reinterpret_cast<const float4*>(y1)[i];
    a.x += b.x; a.y += b.y; a.z += b.z; a.w += b.w;
    reinterpret_cast<float4*>(out)[i] = a;
  }
}

extern "C" void kernel_launch(void* const* d_in, const int* in_sizes, int n_in,
                              void* d_out, int out_size, void* d_ws, size_t ws_size,
                              hipStream_t stream) {
  const float* x  = (const float*)d_in[0];
  const float* Wg = (const float*)d_in[1];
  const float* W1 = (const float*)d_in[2];
  const float* b1 = (const float*)d_in[3];
  const float* W2 = (const float*)d_in[4];
  const float* b2 = (const float*)d_in[5];
  float* out = (float*)d_out;

  char* ws = (char*)d_ws;
  unsigned short* W1b = (unsigned short*)ws;                                  // 2 MiB
  unsigned short* W2b = (unsigned short*)(ws + (size_t)2 * 1024 * 1024);      // 2 MiB
  int*   cnt   = (int*)(ws + (size_t)4 * 1024 * 1024);                        // 8 ints
  int*   plist = (int*)(ws + (size_t)4 * 1024 * 1024 + 256);                  // 128 KiB
  float* wlist = (float*)(ws + (size_t)4 * 1024 * 1024 + 256 +
                          (size_t)2 * NE * NPATCH * sizeof(int));             // 128 KiB
  float* y1buf = (float*)(ws + (size_t)8 * 1024 * 1024);                      // 64 MiB

  size_t need = (size_t)8 * 1024 * 1024 + (size_t)NB * NH * NW * NC * sizeof(float);
  int mode = (ws_size >= need) ? 0 : 1;   // 0: slot buffers + combine, 1: atomic

  if (mode == 1)
    hipMemsetAsync(out, 0, (size_t)out_size * sizeof(float), stream);

  convert_kernel<<<dim3(4096), dim3(256), 0, stream>>>(W1, W2, W1b, W2b, cnt, NE * NFF * NC);
  router_kernel<<<dim3(NPATCH), dim3(256), 0, stream>>>(x, Wg, cnt, plist, wlist);

  float* out1 = (mode == 0) ? y1buf : out;
  ffn_kernel<<<dim3(4096), dim3(512), 0, stream>>>(
      x, b1, b2, W1b, W2b, cnt, plist, wlist, out, out1, mode);

  if (mode == 0) {
    int n4 = NB * NH * NW * NC / 4;
    combine_kernel<<<dim3(2048), dim3(256), 0, stream>>>(out, y1buf, n4);
  }
}

// Round 6
// 489.970 us; speedup vs baseline: 1.4144x; 1.4084x over previous
//
#include <hip/hip_runtime.h>
#include <hip/hip_bf16.h>
#include <cstdint>

// Problem constants (fixed by the reference)
#define NB 4
#define NH 128
#define NW 128
#define NC 256
#define NFF 1024
#define NE 4
#define NPATCH 4096   // B * 32 * 32
#define NPAIR 16      // ordered expert pairs (i1*4+i2), 12 valid
#define PPB 4         // patches per ffn block
#define BM 64         // token rows per ffn block (PPB*16)
#define FFC 256       // FF chunk streamed through LDS
// chunks per expert = NFF/FFC = 4; pipeline iters = 8 (+1 drain)

typedef __attribute__((ext_vector_type(8))) short short8;
typedef __attribute__((ext_vector_type(8))) unsigned short ushort8;
typedef __attribute__((ext_vector_type(4))) float f32x4;

__device__ __forceinline__ unsigned short f2b(float f) {
  union { float f; uint32_t u; } v; v.f = f;
  uint32_t u = v.u + 0x7FFFu + ((v.u >> 16) & 1u);   // RNE
  return (unsigned short)(u >> 16);
}

// tanh-form GELU via sigmoid: x * sigmoid(1.5957691(x + 0.044715 x^3))
__device__ __forceinline__ float gelu_f(float v) {
  float u = v * v;
  float t = __builtin_fmaf(u, 0.044715f, 1.0f) * v;
  float e = __builtin_amdgcn_exp2f(t * -2.3022083f);   // exp(-1.59577*t)
  return v * __builtin_amdgcn_rcpf(1.0f + e);
}

// barrier that drains LDS ops only (no vmcnt drain -> global loads stay in flight)
__device__ __forceinline__ void bar_lgkm() {
  asm volatile("s_waitcnt lgkmcnt(0)" ::: "memory");
  __builtin_amdgcn_s_barrier();
}

// ---------------- weight fp32 -> bf16 (+ cnt zeroing) ----------------
__global__ __launch_bounds__(256) void convert_kernel(
    const float* __restrict__ W1, const float* __restrict__ W2,
    unsigned short* __restrict__ W1b, unsigned short* __restrict__ W2b,
    int* __restrict__ cnt, int n) {
  int i = blockIdx.x * blockDim.x + threadIdx.x;
  if (i < NPAIR) cnt[i] = 0;
  if (i < n) {
    W1b[i] = f2b(W1[i]);
    W2b[i] = f2b(W2[i]);
  }
}

// ---------------- router: means -> logits -> softmax -> top2 -> pair bins ----------------
__global__ __launch_bounds__(256) void router_kernel(
    const float* __restrict__ x, const float* __restrict__ Wg,
    int* __restrict__ cnt, int* __restrict__ plist, float2* __restrict__ wlist) {
  int p = blockIdx.x;                 // 0..4095
  int b = p >> 10, pi = p & 1023;
  int phi = pi >> 5, pwi = pi & 31;
  int c = threadIdx.x;                // 0..255 = channel

  const float* base = x + (((size_t)(b * NH + phi * 4) * NW) + pwi * 4) * NC + c;
  float s = 0.f;
#pragma unroll
  for (int i = 0; i < 4; i++)
#pragma unroll
    for (int j = 0; j < 4; j++)
      s += base[(i * NW + j) * NC];
  float mean = s * (1.f / 16.f);

  __shared__ float m_lds[NC];
  __shared__ double logit_lds[NE];
  m_lds[c] = mean;
  __syncthreads();

  int wid = c >> 6, lane = c & 63;    // wave w computes logit for expert w
  {
    const float* wg = Wg + wid * NC;
    double acc = 0.0;
#pragma unroll
    for (int q = 0; q < 4; q++)
      acc += (double)m_lds[lane + q * 64] * (double)wg[lane + q * 64];
    for (int off = 32; off; off >>= 1) acc += __shfl_down(acc, off);
    if (lane == 0) logit_lds[wid] = acc;
  }
  __syncthreads();

  if (c == 0) {
    double l[NE], pp[NE];
    double mx = -1e300;
#pragma unroll
    for (int i = 0; i < NE; i++) { l[i] = logit_lds[i]; mx = fmax(mx, l[i]); }
    double sum = 0.0;
#pragma unroll
    for (int i = 0; i < NE; i++) { pp[i] = exp(l[i] - mx); sum += pp[i]; }
#pragma unroll
    for (int i = 0; i < NE; i++) pp[i] /= sum;
    // top-2, ties -> lower index (lax.top_k semantics)
    int i1 = 0; double p1 = pp[0];
    for (int i = 1; i < NE; i++) if (pp[i] > p1) { p1 = pp[i]; i1 = i; }
    int i2 = -1; double p2 = -1.0;
    for (int i = 0; i < NE; i++) {
      if (i == i1) continue;
      if (pp[i] > p2) { p2 = pp[i]; i2 = i; }
    }
    double den = p1 + p2 + 1e-9;
    float w1 = (float)(p1 / den), w2 = (float)(p2 / den);
    int pr = i1 * NE + i2;                         // ordered pair bin
    int pos = atomicAdd(&cnt[pr], 1);
    plist[pr * NPATCH + pos] = p;
    wlist[pr * NPATCH + pos] = make_float2(w1, w2);
  }
}

// ---------------- fused pair-FFN: both experts of 4 patches per block ----------------
// 256 thr / 4 waves. GEMM1 (swapped, H^T = W1*X^T): wave = f-strip 64, all 64
// tokens (ftl=4, nt=4 -> 4-way reuse of both operands). GEMM2: wave = c-strip
// 64, all 64 tokens (ct=4, rt=4). Per-patch router weight folded into H after
// GELU, so acc2 accumulates w_A*y_A + w_B*y_B across all 8 chunks (2 experts
// x 4 FF-chunks). 9-phase pipeline: GEMM1(i); [GEMM2(i-1) || GELU(i)->hreg];
// bar; write Hl; bar. Weights read exactly once per block (2 MB / 268 MFLOP).
__global__ __launch_bounds__(256, 2) void ffn_kernel(
    const float* __restrict__ x, const float* __restrict__ b1,
    const float* __restrict__ b2, const unsigned short* __restrict__ W1b,
    const unsigned short* __restrict__ W2b, const int* __restrict__ cnt,
    const int* __restrict__ plist, const float2* __restrict__ wlist,
    float* __restrict__ out) {
  __shared__ unsigned short Xl[BM * NC];    // 32 KiB, swizzled, row stride 512B
  __shared__ unsigned short Hl[BM * FFC];   // 32 KiB, swizzled, row stride 512B

  int bid = blockIdx.x;
  int pr = bid & 15;                  // pair bin (also spreads XCDs)
  int e1 = pr >> 2, e2 = pr & 3;
  int tile = bid >> 4;
  int n = cnt[pr];
  int pbase = tile * PPB;
  if (pbase >= n) return;

  int tid = threadIdx.x, lane = tid & 63, wid = tid >> 6;
  int l15 = lane & 15;
  int kgrp = (lane >> 4) * 8;

  const int*    pl = plist + pr * NPATCH + pbase;
  const float2* wl = wlist + pr * NPATCH + pbase;

  // per-patch router weights (wave-uniform scalar loads)
  float wvA[PPB], wvB[PPB];
#pragma unroll
  for (int q = 0; q < PPB; q++) {
    if (pbase + q < n) { float2 w = wl[q]; wvA[q] = w.x; wvB[q] = w.y; }
    else { wvA[q] = 0.f; wvB[q] = 0.f; }
  }

  // ---- gather tokens -> bf16 LDS (swizzled, 16B writes) ----
  {
    int r  = tid >> 2;            // 0..63 token row; r>>4 = patch slot
    int c0 = (tid & 3) * 64;      // 64 channels per thread
    int pid = (pbase + (r >> 4) < n) ? pl[r >> 4] : -1;
    int t = r & 15;
    if (pid >= 0) {
      int b = pid >> 10, pi = pid & 1023;
      int phi = pi >> 5, pwi = pi & 31;
      const float* src =
          x + (((size_t)(b * NH + phi * 4 + (t >> 2)) * NW) + pwi * 4 + (t & 3)) * NC + c0;
#pragma unroll
      for (int q = 0; q < 8; q++) {
        float4 v0 = *reinterpret_cast<const float4*>(src + q * 8);
        float4 v1 = *reinterpret_cast<const float4*>(src + q * 8 + 4);
        ushort8 h;
        h[0] = f2b(v0.x); h[1] = f2b(v0.y); h[2] = f2b(v0.z); h[3] = f2b(v0.w);
        h[4] = f2b(v1.x); h[5] = f2b(v1.y); h[6] = f2b(v1.z); h[7] = f2b(v1.w);
        int boff = (r * 512 + (c0 + q * 8) * 2) ^ ((r & 7) << 4);
        *reinterpret_cast<ushort8*>((char*)Xl + boff) = h;
      }
    } else {
      ushort8 h = (ushort8)0;
#pragma unroll
      for (int q = 0; q < 8; q++) {
        int boff = (r * 512 + (c0 + q * 8) * 2) ^ ((r & 7) << 4);
        *reinterpret_cast<ushort8*>((char*)Xl + boff) = h;
      }
    }
  }
  bar_lgkm();

  const unsigned short* W1A = W1b + (size_t)e1 * NFF * NC;
  const unsigned short* W1B = W1b + (size_t)e2 * NFF * NC;
  const unsigned short* W2A = W2b + (size_t)e1 * NC * NFF;
  const unsigned short* W2B = W2b + (size_t)e2 * NC * NFF;
  const float* b1A = b1 + e1 * NFF;
  const float* b1B = b1 + e2 * NFF;

  f32x4 acc2[4][4];   // [ct][rt]: Y[rt*16.., wid*64 + ct*16..], both experts
#pragma unroll
  for (int a = 0; a < 4; a++)
#pragma unroll
    for (int b = 0; b < 4; b++)
#pragma unroll
      for (int j = 0; j < 4; j++) acc2[a][b][j] = 0.f;

  f32x4 acc1[4][4];   // [ftl][nt] GEMM1 chunk accumulator
  ushort4 hreg[16];   // GELU output staging (write after barrier)

  // GEMM1 chunk: acc1 = W1[f-strip, :] * X^T   (reads Xl + W1 global)
  auto GEMM1 = [&](const unsigned short* W1e, int fc) {
#pragma unroll
    for (int a = 0; a < 4; a++)
#pragma unroll
      for (int b = 0; b < 4; b++)
#pragma unroll
        for (int j = 0; j < 4; j++) acc1[a][b][j] = 0.f;
#pragma unroll
    for (int ks = 0; ks < 8; ks++) {        // K = NC = 256
      int k = ks * 32 + kgrp;
      short8 bX[4];
#pragma unroll
      for (int nt = 0; nt < 4; nt++) {
        int row = nt * 16 + l15;
        int boff = (row * 512 + k * 2) ^ ((row & 7) << 4);
        bX[nt] = *reinterpret_cast<const short8*>((const char*)Xl + boff);
      }
#pragma unroll
      for (int ftl = 0; ftl < 4; ftl++) {
        int f = fc * FFC + wid * 64 + ftl * 16 + l15;
        short8 aW = *reinterpret_cast<const short8*>(W1e + (size_t)f * NC + k);
#pragma unroll
        for (int nt = 0; nt < 4; nt++)
          acc1[ftl][nt] = __builtin_amdgcn_mfma_f32_16x16x32_bf16(aW, bX[nt], acc1[ftl][nt], 0, 0, 0);
      }
    }
  };

  // GEMM2(prev chunk from Hl) interleaved with GELU(current acc1)->hreg
  auto FUSED = [&](const unsigned short* W2p, int fcp,
                   const float* b1e, int fc, bool sideB, bool domfma) {
#pragma unroll
    for (int ks = 0; ks < 8; ks++) {        // K = FFC = 256
      if (domfma) {
        int kf = ks * 32 + kgrp;
        short8 aH[4];
#pragma unroll
        for (int rt = 0; rt < 4; rt++) {
          int row = rt * 16 + l15;
          int boff = (row * 512 + kf * 2) ^ ((row & 7) << 4);
          aH[rt] = *reinterpret_cast<const short8*>((const char*)Hl + boff);
        }
#pragma unroll
        for (int ct = 0; ct < 4; ct++) {
          int c = wid * 64 + ct * 16 + l15;
          short8 bW = *reinterpret_cast<const short8*>(W2p + (size_t)c * NFF + fcp * FFC + kf);
#pragma unroll
          for (int rt = 0; rt < 4; rt++)
            acc2[ct][rt] = __builtin_amdgcn_mfma_f32_16x16x32_bf16(aH[rt], bW, acc2[ct][rt], 0, 0, 0);
        }
      }
      // two GELU groups per ks (16 total): g -> (ftl, nt)
#pragma unroll
      for (int j = 0; j < 2; j++) {
        int g = ks * 2 + j;
        int ftl = g >> 2, nt = g & 3;
        int f0 = wid * 64 + ftl * 16 + (lane >> 4) * 4;
        float4 bv = *reinterpret_cast<const float4*>(b1e + fc * FFC + f0);
        float w = sideB ? wvB[nt] : wvA[nt];
        ushort4 hp;
        hp.x = f2b(gelu_f(acc1[ftl][nt][0] + bv.x) * w);
        hp.y = f2b(gelu_f(acc1[ftl][nt][1] + bv.y) * w);
        hp.z = f2b(gelu_f(acc1[ftl][nt][2] + bv.z) * w);
        hp.w = f2b(gelu_f(acc1[ftl][nt][3] + bv.w) * w);
        hreg[g] = hp;
      }
    }
  };

  auto WRITEH = [&]() {
#pragma unroll
    for (int g = 0; g < 16; g++) {
      int ftl = g >> 2, nt = g & 3;
      int token = nt * 16 + l15;
      int f0 = wid * 64 + ftl * 16 + (lane >> 4) * 4;
      int boff = (token * 512 + f0 * 2) ^ ((token & 7) << 4);
      *reinterpret_cast<ushort4*>((char*)Hl + boff) = hreg[g];
    }
  };

  // ---- 9-phase pipeline over 8 chunks (expert A: 0..3, expert B: 4..7) ----
  GEMM1(W1A, 0);
  FUSED(nullptr, 0, b1A, 0, false, false);   // GELU only
  WRITEH();
  bar_lgkm();

#pragma unroll 1
  for (int i = 1; i < 8; i++) {
    bool sB = (i >= 4);
    int fc = i & 3, fcp = (i - 1) & 3;
    const unsigned short* W1e = sB ? W1B : W1A;
    const float* b1e = sB ? b1B : b1A;
    const unsigned short* W2p = (i - 1 >= 4) ? W2B : W2A;
    GEMM1(W1e, fc);
    FUSED(W2p, fcp, b1e, fc, sB, true);
    bar_lgkm();       // all waves done reading Hl
    WRITEH();
    bar_lgkm();       // new H visible
  }

  // drain: GEMM2 of last chunk (expert B, chunk 3)
  {
#pragma unroll
    for (int ks = 0; ks < 8; ks++) {
      int kf = ks * 32 + kgrp;
      short8 aH[4];
#pragma unroll
      for (int rt = 0; rt < 4; rt++) {
        int row = rt * 16 + l15;
        int boff = (row * 512 + kf * 2) ^ ((row & 7) << 4);
        aH[rt] = *reinterpret_cast<const short8*>((const char*)Hl + boff);
      }
#pragma unroll
      for (int ct = 0; ct < 4; ct++) {
        int c = wid * 64 + ct * 16 + l15;
        short8 bW = *reinterpret_cast<const short8*>(W2B + (size_t)c * NFF + 3 * FFC + kf);
#pragma unroll
        for (int rt = 0; rt < 4; rt++)
          acc2[ct][rt] = __builtin_amdgcn_mfma_f32_16x16x32_bf16(aH[rt], bW, acc2[ct][rt], 0, 0, 0);
      }
    }
  }

  // ---- epilogue: out = acc2 + wA*b2[e1] + wB*b2[e2], plain stores ----
  float b2A4[4], b2B4[4];
#pragma unroll
  for (int ct = 0; ct < 4; ct++) {
    int c = wid * 64 + ct * 16 + l15;
    b2A4[ct] = b2[e1 * NC + c];
    b2B4[ct] = b2[e2 * NC + c];
  }
#pragma unroll
  for (int rt = 0; rt < 4; rt++) {
    if (pbase + rt >= n) continue;
    int pid = pl[rt];
    float wA = wvA[rt], wB = wvB[rt];
    int b = pid >> 10, pi = pid & 1023;
    int phi = pi >> 5, pwi = pi & 31;
#pragma unroll
    for (int i2 = 0; i2 < 4; i2++) {
      int t = (lane >> 4) * 4 + i2;   // token within patch
      float* dst =
          out + (((size_t)(b * NH + phi * 4 + (t >> 2)) * NW) + pwi * 4 + (t & 3)) * NC;
#pragma unroll
      for (int ct = 0; ct < 4; ct++) {
        int c = wid * 64 + ct * 16 + l15;
        dst[c] = acc2[ct][rt][i2] + wA * b2A4[ct] + wB * b2B4[ct];
      }
    }
  }
}

extern "C" void kernel_launch(void* const* d_in, const int* in_sizes, int n_in,
                              void* d_out, int out_size, void* d_ws, size_t ws_size,
                              hipStream_t stream) {
  const float* x  = (const float*)d_in[0];
  const float* Wg = (const float*)d_in[1];
  const float* W1 = (const float*)d_in[2];
  const float* b1 = (const float*)d_in[3];
  const float* W2 = (const float*)d_in[4];
  const float* b2 = (const float*)d_in[5];
  float* out = (float*)d_out;

  char* ws = (char*)d_ws;
  unsigned short* W1b = (unsigned short*)ws;                                  // 2 MiB
  unsigned short* W2b = (unsigned short*)(ws + (size_t)2 * 1024 * 1024);      // 2 MiB
  int*    cnt   = (int*)(ws + (size_t)4 * 1024 * 1024);                       // 64 B
  int*    plist = (int*)(ws + (size_t)4 * 1024 * 1024 + 256);                 // 256 KiB
  float2* wlist = (float2*)(ws + (size_t)4 * 1024 * 1024 + 256 +
                            (size_t)NPAIR * NPATCH * sizeof(int));            // 512 KiB

  convert_kernel<<<dim3(4096), dim3(256), 0, stream>>>(W1, W2, W1b, W2b, cnt, NE * NFF * NC);
  router_kernel<<<dim3(NPATCH), dim3(256), 0, stream>>>(x, Wg, cnt, plist, wlist);

  ffn_kernel<<<dim3(NPAIR * (NPATCH / PPB)), dim3(256), 0, stream>>>(
      x, b1, b2, W1b, W2b, cnt, plist, wlist, out);
}

// Round 7
// 460.981 us; speedup vs baseline: 1.5034x; 1.0629x over previous
//
#include <hip/hip_runtime.h>
#include <hip/hip_bf16.h>
#include <cstdint>

// Problem constants (fixed by the reference)
#define NB 4
#define NH 128
#define NW 128
#define NC 256
#define NFF 1024
#define NE 4
#define NPATCH 4096   // B * 32 * 32
#define NPAIR 16      // ordered expert pairs (i1*4+i2), 12 valid
#define PPB 4         // patches per ffn block
#define BM 64         // token rows per ffn block (PPB*16)
#define FFC 256       // FF chunk streamed through LDS
// 8 chunks total: expert A chunks 0..3, expert B chunks 4..7

typedef __attribute__((ext_vector_type(8))) short short8;
typedef __attribute__((ext_vector_type(8))) unsigned short ushort8;
typedef __attribute__((ext_vector_type(4))) float f32x4;

__device__ __forceinline__ unsigned short f2b(float f) {
  union { float f; uint32_t u; } v; v.f = f;
  uint32_t u = v.u + 0x7FFFu + ((v.u >> 16) & 1u);   // RNE
  return (unsigned short)(u >> 16);
}

// tanh-form GELU via sigmoid: x * sigmoid(1.5957691(x + 0.044715 x^3))
__device__ __forceinline__ float gelu_f(float v) {
  float u = v * v;
  float t = __builtin_fmaf(u, 0.044715f, 1.0f) * v;
  float e = __builtin_amdgcn_exp2f(t * -2.3022083f);   // exp(-1.59577*t)
  return v * __builtin_amdgcn_rcpf(1.0f + e);
}

// barrier that drains LDS ops only (no vmcnt drain -> global loads stay in flight)
__device__ __forceinline__ void bar_lgkm() {
  asm volatile("s_waitcnt lgkmcnt(0)" ::: "memory");
  __builtin_amdgcn_s_barrier();
}

// ---------------- weight fp32 -> bf16 (+ cnt zeroing) ----------------
__global__ __launch_bounds__(256) void convert_kernel(
    const float* __restrict__ W1, const float* __restrict__ W2,
    unsigned short* __restrict__ W1b, unsigned short* __restrict__ W2b,
    int* __restrict__ cnt, int n) {
  int i = blockIdx.x * blockDim.x + threadIdx.x;
  if (i < NPAIR) cnt[i] = 0;
  if (i < n) {
    W1b[i] = f2b(W1[i]);
    W2b[i] = f2b(W2[i]);
  }
}

// ---------------- router: means -> logits -> softmax -> top2 -> pair bins ----------------
__global__ __launch_bounds__(256) void router_kernel(
    const float* __restrict__ x, const float* __restrict__ Wg,
    int* __restrict__ cnt, int* __restrict__ plist, float2* __restrict__ wlist) {
  int p = blockIdx.x;                 // 0..4095
  int b = p >> 10, pi = p & 1023;
  int phi = pi >> 5, pwi = pi & 31;
  int c = threadIdx.x;                // 0..255 = channel

  const float* base = x + (((size_t)(b * NH + phi * 4) * NW) + pwi * 4) * NC + c;
  float s = 0.f;
#pragma unroll
  for (int i = 0; i < 4; i++)
#pragma unroll
    for (int j = 0; j < 4; j++)
      s += base[(i * NW + j) * NC];
  float mean = s * (1.f / 16.f);

  __shared__ float m_lds[NC];
  __shared__ double logit_lds[NE];
  m_lds[c] = mean;
  __syncthreads();

  int wid = c >> 6, lane = c & 63;    // wave w computes logit for expert w
  {
    const float* wg = Wg + wid * NC;
    double acc = 0.0;
#pragma unroll
    for (int q = 0; q < 4; q++)
      acc += (double)m_lds[lane + q * 64] * (double)wg[lane + q * 64];
    for (int off = 32; off; off >>= 1) acc += __shfl_down(acc, off);
    if (lane == 0) logit_lds[wid] = acc;
  }
  __syncthreads();

  if (c == 0) {
    double l[NE], pp[NE];
    double mx = -1e300;
#pragma unroll
    for (int i = 0; i < NE; i++) { l[i] = logit_lds[i]; mx = fmax(mx, l[i]); }
    double sum = 0.0;
#pragma unroll
    for (int i = 0; i < NE; i++) { pp[i] = exp(l[i] - mx); sum += pp[i]; }
#pragma unroll
    for (int i = 0; i < NE; i++) pp[i] /= sum;
    // top-2, ties -> lower index (lax.top_k semantics)
    int i1 = 0; double p1 = pp[0];
    for (int i = 1; i < NE; i++) if (pp[i] > p1) { p1 = pp[i]; i1 = i; }
    int i2 = -1; double p2 = -1.0;
    for (int i = 0; i < NE; i++) {
      if (i == i1) continue;
      if (pp[i] > p2) { p2 = pp[i]; i2 = i; }
    }
    double den = p1 + p2 + 1e-9;
    float w1 = (float)(p1 / den), w2 = (float)(p2 / den);
    int pr = i1 * NE + i2;                         // ordered pair bin
    int pos = atomicAdd(&cnt[pr], 1);
    plist[pr * NPATCH + pos] = p;
    wlist[pr * NPATCH + pos] = make_float2(w1, w2);
  }
}

// ---------------- worklist: compact (bin, tile) pairs ----------------
// wl[0] = count; wl[1+i] = (pr << 12) | pbase
__global__ __launch_bounds__(64) void worklist_kernel(
    const int* __restrict__ cnt, int* __restrict__ wl) {
  int lane = threadIdx.x;
  if (lane < NPAIR) {
    int base = 0, mynb = 0;
    for (int q = 0; q < NPAIR; ++q) {
      int nb = (cnt[q] + PPB - 1) / PPB;
      if (q < lane) base += nb;
      if (q == lane) mynb = nb;
    }
    for (int i = 0; i < mynb; ++i)
      wl[1 + base + i] = (lane << 12) | (i * PPB);
    if (lane == NPAIR - 1) wl[0] = base + mynb;
  }
}

// ---------------- pair-FFN, producer/consumer wave specialization ----------------
// 512 thr / 8 waves, 1 block/CU (96 KiB LDS). Waves 0-3 (G1): GEMM1 (swapped,
// H^T = W1*X^T, f-strip 64 each) + bias + GELU + router-weight scale, write
// bf16 H into double-buffered Hl. Waves 4-7 (G2): GEMM2 (Y += H*W2^T,
// c-strip 64 each), acc2 held across all 8 chunks (2 experts x 4 chunks).
// Each SIMD hosts 1 G1 + 1 G2 wave -> G1's VALU/L2-loads overlap G2's MFMAs.
// Each role has only ONE 64-reg accumulator -> ~190 arch VGPRs for the
// compiler to pipeline weight loads 2-3 ks deep. One lgkm-only barrier per
// chunk: G1 produces chunk j+1 into Hl[(j+1)&1] while G2 consumes chunk j
// from Hl[j&1]. Barrier counts: G1 = 8 (end of each chunk), G2 = 1 + 7.
__global__ __launch_bounds__(512, 2) void ffn_kernel(
    const float* __restrict__ x, const float* __restrict__ b1,
    const float* __restrict__ b2, const unsigned short* __restrict__ W1b,
    const unsigned short* __restrict__ W2b, const int* __restrict__ cnt,
    const int* __restrict__ plist, const float2* __restrict__ wlist,
    const int* __restrict__ wl, float* __restrict__ out) {
  __shared__ unsigned short Xl[BM * NC];        // 32 KiB, swizzled, stride 512B
  __shared__ unsigned short Hl[2][BM * FFC];    // 2 x 32 KiB, swizzled

  int bid = blockIdx.x;
  if (bid >= wl[0]) return;
  int ent = wl[1 + bid];
  int pr = ent >> 12, pbase = ent & 4095;
  int e1 = pr >> 2, e2 = pr & 3;
  int n = cnt[pr];

  int tid = threadIdx.x, lane = tid & 63, wid = tid >> 6;
  int l15 = lane & 15;
  int kgrp = (lane >> 4) * 8;

  const int*    pl  = plist + pr * NPATCH + pbase;
  const float2* wlp = wlist + pr * NPATCH + pbase;

  float wvA[PPB], wvB[PPB];
#pragma unroll
  for (int q = 0; q < PPB; q++) {
    if (pbase + q < n) { float2 w = wlp[q]; wvA[q] = w.x; wvB[q] = w.y; }
    else { wvA[q] = 0.f; wvB[q] = 0.f; }
  }

  // ---- gather tokens -> bf16 LDS (all 8 waves) ----
  {
    int r  = tid >> 3;            // 0..63 token row
    int c0 = (tid & 7) * 32;      // 32 channels per thread
    int pid = (pbase + (r >> 4) < n) ? pl[r >> 4] : -1;
    int t = r & 15;
    if (pid >= 0) {
      int b = pid >> 10, pi = pid & 1023;
      int phi = pi >> 5, pwi = pi & 31;
      const float* src =
          x + (((size_t)(b * NH + phi * 4 + (t >> 2)) * NW) + pwi * 4 + (t & 3)) * NC + c0;
#pragma unroll
      for (int q = 0; q < 4; q++) {
        float4 v0 = *reinterpret_cast<const float4*>(src + q * 8);
        float4 v1 = *reinterpret_cast<const float4*>(src + q * 8 + 4);
        ushort8 h;
        h[0] = f2b(v0.x); h[1] = f2b(v0.y); h[2] = f2b(v0.z); h[3] = f2b(v0.w);
        h[4] = f2b(v1.x); h[5] = f2b(v1.y); h[6] = f2b(v1.z); h[7] = f2b(v1.w);
        int boff = (r * 512 + (c0 + q * 8) * 2) ^ ((r & 7) << 4);
        *reinterpret_cast<ushort8*>((char*)Xl + boff) = h;
      }
    } else {
      ushort8 h = (ushort8)0;
#pragma unroll
      for (int q = 0; q < 4; q++) {
        int boff = (r * 512 + (c0 + q * 8) * 2) ^ ((r & 7) << 4);
        *reinterpret_cast<ushort8*>((char*)Xl + boff) = h;
      }
    }
  }
  bar_lgkm();   // X visible to all waves

  if (wid < 4) {
    // ================= G1: producer =================
    int wf = wid;
    const unsigned short* W1A = W1b + (size_t)e1 * NFF * NC;
    const unsigned short* W1B = W1b + (size_t)e2 * NFF * NC;
    const float* b1A = b1 + e1 * NFF;
    const float* b1B = b1 + e2 * NFF;

    f32x4 acc1[4][4];   // [ftl][nt]
    ushort4 hreg[16];

#pragma unroll 1
    for (int j = 0; j < 8; ++j) {
      const unsigned short* W1e = (j < 4) ? W1A : W1B;
      const float* b1e = (j < 4) ? b1A : b1B;
      int fc = j & 3;
#pragma unroll
      for (int a = 0; a < 4; a++)
#pragma unroll
        for (int b = 0; b < 4; b++)
#pragma unroll
          for (int q = 0; q < 4; q++) acc1[a][b][q] = 0.f;

#pragma unroll
      for (int ks = 0; ks < 8; ++ks) {        // K = NC = 256
        int k = ks * 32 + kgrp;
        short8 bX[4];
#pragma unroll
        for (int nt = 0; nt < 4; nt++) {
          int row = nt * 16 + l15;
          int boff = (row * 512 + k * 2) ^ ((row & 7) << 4);
          bX[nt] = *reinterpret_cast<const short8*>((const char*)Xl + boff);
        }
        short8 aW[4];
#pragma unroll
        for (int ftl = 0; ftl < 4; ftl++) {
          int f = fc * FFC + wf * 64 + ftl * 16 + l15;
          aW[ftl] = *reinterpret_cast<const short8*>(W1e + (size_t)f * NC + k);
        }
        __builtin_amdgcn_s_setprio(1);
#pragma unroll
        for (int ftl = 0; ftl < 4; ftl++)
#pragma unroll
          for (int nt = 0; nt < 4; nt++)
            acc1[ftl][nt] = __builtin_amdgcn_mfma_f32_16x16x32_bf16(
                aW[ftl], bX[nt], acc1[ftl][nt], 0, 0, 0);
        __builtin_amdgcn_s_setprio(0);
      }

      // bias + gelu + router-weight scale -> hreg
#pragma unroll
      for (int ftl = 0; ftl < 4; ftl++) {
        int f0 = wf * 64 + ftl * 16 + (lane >> 4) * 4;
        float4 bv = *reinterpret_cast<const float4*>(b1e + fc * FFC + f0);
#pragma unroll
        for (int nt = 0; nt < 4; nt++) {
          float w = (j < 4) ? wvA[nt] : wvB[nt];
          ushort4 hp;
          hp.x = f2b(gelu_f(acc1[ftl][nt][0] + bv.x) * w);
          hp.y = f2b(gelu_f(acc1[ftl][nt][1] + bv.y) * w);
          hp.z = f2b(gelu_f(acc1[ftl][nt][2] + bv.z) * w);
          hp.w = f2b(gelu_f(acc1[ftl][nt][3] + bv.w) * w);
          hreg[ftl * 4 + nt] = hp;
        }
      }
      unsigned short* Hb = &Hl[j & 1][0];
#pragma unroll
      for (int g = 0; g < 16; ++g) {
        int ftl = g >> 2, nt = g & 3;
        int token = nt * 16 + l15;
        int f0 = wf * 64 + ftl * 16 + (lane >> 4) * 4;
        int boff = (token * 512 + f0 * 2) ^ ((token & 7) << 4);
        *reinterpret_cast<ushort4*>((char*)Hb + boff) = hreg[g];
      }
      bar_lgkm();   // chunk j published; G2 done with Hl[j&1]'s previous tenant
    }
    // G1 done (8 barriers executed)
  } else {
    // ================= G2: consumer =================
    int wc = wid - 4;
    const unsigned short* W2A = W2b + (size_t)e1 * NC * NFF;
    const unsigned short* W2B = W2b + (size_t)e2 * NC * NFF;

    f32x4 acc2[4][4];   // [ct][rt]
#pragma unroll
    for (int a = 0; a < 4; a++)
#pragma unroll
      for (int b = 0; b < 4; b++)
#pragma unroll
        for (int q = 0; q < 4; q++) acc2[a][b][q] = 0.f;

    bar_lgkm();   // wait for chunk 0

#pragma unroll 1
    for (int j = 0; j < 8; ++j) {
      const unsigned short* W2e = (j < 4) ? W2A : W2B;
      int fcp = j & 3;
      const unsigned short* Hb = &Hl[j & 1][0];
#pragma unroll
      for (int ks = 0; ks < 8; ++ks) {        // K = FFC = 256
        int kf = ks * 32 + kgrp;
        short8 aH[4];
#pragma unroll
        for (int rt = 0; rt < 4; rt++) {
          int row = rt * 16 + l15;
          int boff = (row * 512 + kf * 2) ^ ((row & 7) << 4);
          aH[rt] = *reinterpret_cast<const short8*>((const char*)Hb + boff);
        }
        short8 bW[4];
#pragma unroll
        for (int ct = 0; ct < 4; ct++) {
          int c = wc * 64 + ct * 16 + l15;
          bW[ct] = *reinterpret_cast<const short8*>(
              W2e + (size_t)c * NFF + fcp * FFC + kf);
        }
        __builtin_amdgcn_s_setprio(1);
#pragma unroll
        for (int ct = 0; ct < 4; ct++)
#pragma unroll
          for (int rt = 0; rt < 4; rt++)
            acc2[ct][rt] = __builtin_amdgcn_mfma_f32_16x16x32_bf16(
                aH[rt], bW[ct], acc2[ct][rt], 0, 0, 0);
        __builtin_amdgcn_s_setprio(0);
      }
      if (j < 7) bar_lgkm();   // total G2 barriers: 1 + 7 = 8 ✓
    }

    // ---- epilogue: out = acc2 + wA*b2[e1] + wB*b2[e2] ----
    float b2A4[4], b2B4[4];
#pragma unroll
    for (int ct = 0; ct < 4; ct++) {
      int c = wc * 64 + ct * 16 + l15;
      b2A4[ct] = b2[e1 * NC + c];
      b2B4[ct] = b2[e2 * NC + c];
    }
#pragma unroll
    for (int rt = 0; rt < 4; rt++) {
      if (pbase + rt >= n) continue;
      int pid = pl[rt];
      float wA = wvA[rt], wB = wvB[rt];
      int b = pid >> 10, pi = pid & 1023;
      int phi = pi >> 5, pwi = pi & 31;
#pragma unroll
      for (int i2 = 0; i2 < 4; i2++) {
        int t = (lane >> 4) * 4 + i2;   // token within patch
        float* dst =
            out + (((size_t)(b * NH + phi * 4 + (t >> 2)) * NW) + pwi * 4 + (t & 3)) * NC;
#pragma unroll
        for (int ct = 0; ct < 4; ct++) {
          int c = wc * 64 + ct * 16 + l15;
          dst[c] = acc2[ct][rt][i2] + wA * b2A4[ct] + wB * b2B4[ct];
        }
      }
    }
  }
}

extern "C" void kernel_launch(void* const* d_in, const int* in_sizes, int n_in,
                              void* d_out, int out_size, void* d_ws, size_t ws_size,
                              hipStream_t stream) {
  const float* x  = (const float*)d_in[0];
  const float* Wg = (const float*)d_in[1];
  const float* W1 = (const float*)d_in[2];
  const float* b1 = (const float*)d_in[3];
  const float* W2 = (const float*)d_in[4];
  const float* b2 = (const float*)d_in[5];
  float* out = (float*)d_out;

  char* ws = (char*)d_ws;
  unsigned short* W1b = (unsigned short*)ws;                                  // 2 MiB
  unsigned short* W2b = (unsigned short*)(ws + (size_t)2 * 1024 * 1024);      // 2 MiB
  int*    cnt   = (int*)(ws + (size_t)4 * 1024 * 1024);                       // 64 B
  int*    plist = (int*)(ws + (size_t)4 * 1024 * 1024 + 256);                 // 256 KiB
  float2* wlist = (float2*)(ws + (size_t)4 * 1024 * 1024 + 256 +
                            (size_t)NPAIR * NPATCH * sizeof(int));            // 512 KiB
  int*    wl    = (int*)(ws + (size_t)5 * 1024 * 1024);                       // ~8 KiB

  convert_kernel<<<dim3(4096), dim3(256), 0, stream>>>(W1, W2, W1b, W2b, cnt, NE * NFF * NC);
  router_kernel<<<dim3(NPATCH), dim3(256), 0, stream>>>(x, Wg, cnt, plist, wlist);
  worklist_kernel<<<dim3(1), dim3(64), 0, stream>>>(cnt, wl);

  // max tiles = sum over bins of ceil(n/4) <= 1024 + 12
  ffn_kernel<<<dim3(1040), dim3(512), 0, stream>>>(
      x, b1, b2, W1b, W2b, cnt, plist, wlist, wl, out);
}

// Round 8
// 438.168 us; speedup vs baseline: 1.5816x; 1.0521x over previous
//
#include <hip/hip_runtime.h>
#include <hip/hip_bf16.h>
#include <cstdint>

// Problem constants (fixed by the reference)
#define NB 4
#define NH 128
#define NW 128
#define NC 256
#define NFF 1024
#define NE 4
#define NPATCH 4096   // B * 32 * 32
#define NPAIR 16      // ordered expert pairs (i1*4+i2), 12 valid
#define PPB 4         // patches per ffn block
#define BM 64         // token rows per ffn block (PPB*16)
#define FFC 128       // FF chunk streamed through LDS
#define NCHUNK_TOT 16 // 2 experts x (NFF/FFC)

typedef __attribute__((ext_vector_type(8))) short short8;
typedef __attribute__((ext_vector_type(8))) unsigned short ushort8;
typedef __attribute__((ext_vector_type(4))) float f32x4;

__device__ __forceinline__ unsigned short f2b(float f) {
  union { float f; uint32_t u; } v; v.f = f;
  uint32_t u = v.u + 0x7FFFu + ((v.u >> 16) & 1u);   // RNE
  return (unsigned short)(u >> 16);
}

// tanh-form GELU via sigmoid: x * sigmoid(1.5957691(x + 0.044715 x^3))
__device__ __forceinline__ float gelu_f(float v) {
  float u = v * v;
  float t = __builtin_fmaf(u, 0.044715f, 1.0f) * v;
  float e = __builtin_amdgcn_exp2f(t * -2.3022083f);   // exp(-1.59577*t)
  return v * __builtin_amdgcn_rcpf(1.0f + e);
}

// barrier that drains LDS ops only (no vmcnt drain -> global loads stay in flight)
__device__ __forceinline__ void bar_lgkm() {
  asm volatile("s_waitcnt lgkmcnt(0)" ::: "memory");
  __builtin_amdgcn_s_barrier();
}

// ---------------- weight fp32 -> bf16 (+ cnt zeroing) ----------------
__global__ __launch_bounds__(256) void convert_kernel(
    const float* __restrict__ W1, const float* __restrict__ W2,
    unsigned short* __restrict__ W1b, unsigned short* __restrict__ W2b,
    int* __restrict__ cnt, int n) {
  int i = blockIdx.x * blockDim.x + threadIdx.x;
  if (i < NPAIR) cnt[i] = 0;
  if (i < n) {
    W1b[i] = f2b(W1[i]);
    W2b[i] = f2b(W2[i]);
  }
}

// ---------------- router: means -> logits -> softmax -> top2 -> pair bins ----------------
__global__ __launch_bounds__(256) void router_kernel(
    const float* __restrict__ x, const float* __restrict__ Wg,
    int* __restrict__ cnt, int* __restrict__ plist, float2* __restrict__ wlist) {
  int p = blockIdx.x;                 // 0..4095
  int b = p >> 10, pi = p & 1023;
  int phi = pi >> 5, pwi = pi & 31;
  int c = threadIdx.x;                // 0..255 = channel

  const float* base = x + (((size_t)(b * NH + phi * 4) * NW) + pwi * 4) * NC + c;
  float s = 0.f;
#pragma unroll
  for (int i = 0; i < 4; i++)
#pragma unroll
    for (int j = 0; j < 4; j++)
      s += base[(i * NW + j) * NC];
  float mean = s * (1.f / 16.f);

  __shared__ float m_lds[NC];
  __shared__ double logit_lds[NE];
  m_lds[c] = mean;
  __syncthreads();

  int wid = c >> 6, lane = c & 63;    // wave w computes logit for expert w
  {
    const float* wg = Wg + wid * NC;
    double acc = 0.0;
#pragma unroll
    for (int q = 0; q < 4; q++)
      acc += (double)m_lds[lane + q * 64] * (double)wg[lane + q * 64];
    for (int off = 32; off; off >>= 1) acc += __shfl_down(acc, off);
    if (lane == 0) logit_lds[wid] = acc;
  }
  __syncthreads();

  if (c == 0) {
    double l[NE], pp[NE];
    double mx = -1e300;
#pragma unroll
    for (int i = 0; i < NE; i++) { l[i] = logit_lds[i]; mx = fmax(mx, l[i]); }
    double sum = 0.0;
#pragma unroll
    for (int i = 0; i < NE; i++) { pp[i] = exp(l[i] - mx); sum += pp[i]; }
#pragma unroll
    for (int i = 0; i < NE; i++) pp[i] /= sum;
    // top-2, ties -> lower index (lax.top_k semantics)
    int i1 = 0; double p1 = pp[0];
    for (int i = 1; i < NE; i++) if (pp[i] > p1) { p1 = pp[i]; i1 = i; }
    int i2 = -1; double p2 = -1.0;
    for (int i = 0; i < NE; i++) {
      if (i == i1) continue;
      if (pp[i] > p2) { p2 = pp[i]; i2 = i; }
    }
    double den = p1 + p2 + 1e-9;
    float w1 = (float)(p1 / den), w2 = (float)(p2 / den);
    int pr = i1 * NE + i2;                         // ordered pair bin
    int pos = atomicAdd(&cnt[pr], 1);
    plist[pr * NPATCH + pos] = p;
    wlist[pr * NPATCH + pos] = make_float2(w1, w2);
  }
}

// ---------------- worklist: XCD-affine padded slots ----------------
// class x (0..7) covers bins {x, x+8}; slot s -> class s%8 (blockIdx%8 ~ XCD).
// wl[0] = slot count (8 * max class tiles); wl[1+s] = (pr<<12)|pbase or -1.
__global__ __launch_bounds__(64) void worklist_kernel(
    const int* __restrict__ cnt, int* __restrict__ wl) {
  int lane = threadIdx.x;
  int cA[8], cB[8], mx = 0;
#pragma unroll
  for (int xc = 0; xc < 8; ++xc) {
    cA[xc] = (cnt[xc] + PPB - 1) / PPB;
    cB[xc] = (cnt[xc + 8] + PPB - 1) / PPB;
    int t = cA[xc] + cB[xc];
    mx = (t > mx) ? t : mx;
  }
  if (lane == 0) wl[0] = 8 * mx;
  int x = lane & 7, sub = lane >> 3;     // 8 writer lanes per class
  int nA = cA[x], tot = cA[x] + cB[x];
  for (int r = sub; r < mx; r += 8) {
    int ent = -1;
    if (r < nA) ent = (x << 12) | (r * PPB);
    else if (r < tot) ent = ((x + 8) << 12) | ((r - nA) * PPB);
    wl[1 + x + 8 * r] = ent;
  }
}

// ---------------- pair-FFN, producer/consumer wave specialization ----------------
// 512 thr / 8 waves, 64 KiB LDS -> 2 blocks/CU (4 waves/SIMD: 2 G1 + 2 G2
// from desynced blocks = the latency-hiding TLP). Waves 0-3 (G1): GEMM1
// (swapped, H^T = W1*X^T, f-strip 32 of each 128-wide chunk) + bias + GELU +
// router-weight scale -> double-buffered Hl. Waves 4-7 (G2): GEMM2
// (Y += H*W2^T, c-strip 64), acc2 held across all 16 chunks (2 experts x 8).
// One lgkm-only barrier per chunk. launch_bounds(512,4) caps VGPR at 128
// (fits: G1 ~90, G2 ~120 - this is why the role split matters).
__global__ __launch_bounds__(512, 4) void ffn_kernel(
    const float* __restrict__ x, const float* __restrict__ b1,
    const float* __restrict__ b2, const unsigned short* __restrict__ W1b,
    const unsigned short* __restrict__ W2b, const int* __restrict__ cnt,
    const int* __restrict__ plist, const float2* __restrict__ wlist,
    const int* __restrict__ wl, float* __restrict__ out) {
  __shared__ unsigned short Xl[BM * NC];        // 32 KiB, swizzled, stride 512B
  __shared__ unsigned short Hl[2][BM * FFC];    // 2 x 16 KiB, swizzled, stride 256B

  int slot = blockIdx.x;
  if (slot >= wl[0]) return;
  int ent = wl[1 + slot];
  if (ent < 0) return;
  int pr = ent >> 12, pbase = ent & 4095;
  int e1 = pr >> 2, e2 = pr & 3;
  int n = cnt[pr];

  int tid = threadIdx.x, lane = tid & 63, wid = tid >> 6;
  int l15 = lane & 15;
  int kgrp = (lane >> 4) * 8;

  const int*    pl  = plist + pr * NPATCH + pbase;
  const float2* wlp = wlist + pr * NPATCH + pbase;

  float wvA[PPB], wvB[PPB];
#pragma unroll
  for (int q = 0; q < PPB; q++) {
    if (pbase + q < n) { float2 w = wlp[q]; wvA[q] = w.x; wvB[q] = w.y; }
    else { wvA[q] = 0.f; wvB[q] = 0.f; }
  }

  // ---- gather tokens -> bf16 LDS (all 8 waves) ----
  {
    int r  = tid >> 3;            // 0..63 token row
    int c0 = (tid & 7) * 32;      // 32 channels per thread
    int pid = (pbase + (r >> 4) < n) ? pl[r >> 4] : -1;
    int t = r & 15;
    if (pid >= 0) {
      int b = pid >> 10, pi = pid & 1023;
      int phi = pi >> 5, pwi = pi & 31;
      const float* src =
          x + (((size_t)(b * NH + phi * 4 + (t >> 2)) * NW) + pwi * 4 + (t & 3)) * NC + c0;
#pragma unroll
      for (int q = 0; q < 4; q++) {
        float4 v0 = *reinterpret_cast<const float4*>(src + q * 8);
        float4 v1 = *reinterpret_cast<const float4*>(src + q * 8 + 4);
        ushort8 h;
        h[0] = f2b(v0.x); h[1] = f2b(v0.y); h[2] = f2b(v0.z); h[3] = f2b(v0.w);
        h[4] = f2b(v1.x); h[5] = f2b(v1.y); h[6] = f2b(v1.z); h[7] = f2b(v1.w);
        int boff = (r * 512 + (c0 + q * 8) * 2) ^ ((r & 7) << 4);
        *reinterpret_cast<ushort8*>((char*)Xl + boff) = h;
      }
    } else {
      ushort8 h = (ushort8)0;
#pragma unroll
      for (int q = 0; q < 4; q++) {
        int boff = (r * 512 + (c0 + q * 8) * 2) ^ ((r & 7) << 4);
        *reinterpret_cast<ushort8*>((char*)Xl + boff) = h;
      }
    }
  }
  bar_lgkm();   // X visible to all waves

  if (wid < 4) {
    // ================= G1: producer =================
    int wf = wid;
    const unsigned short* W1A = W1b + (size_t)e1 * NFF * NC;
    const unsigned short* W1B = W1b + (size_t)e2 * NFF * NC;
    const float* b1A = b1 + e1 * NFF;
    const float* b1B = b1 + e2 * NFF;

    f32x4 acc1[2][4];   // [ftl][nt]
    ushort4 hreg[8];

#pragma unroll 1
    for (int j = 0; j < NCHUNK_TOT; ++j) {
      const unsigned short* W1e = (j < 8) ? W1A : W1B;
      const float* b1e = (j < 8) ? b1A : b1B;
      int fc = j & 7;
#pragma unroll
      for (int a = 0; a < 2; a++)
#pragma unroll
        for (int b = 0; b < 4; b++)
#pragma unroll
          for (int q = 0; q < 4; q++) acc1[a][b][q] = 0.f;

#pragma unroll
      for (int ks = 0; ks < 8; ++ks) {        // K = NC = 256
        int k = ks * 32 + kgrp;
        short8 bX[4];
#pragma unroll
        for (int nt = 0; nt < 4; nt++) {
          int row = nt * 16 + l15;
          int boff = (row * 512 + k * 2) ^ ((row & 7) << 4);
          bX[nt] = *reinterpret_cast<const short8*>((const char*)Xl + boff);
        }
        short8 aW[2];
#pragma unroll
        for (int ftl = 0; ftl < 2; ftl++) {
          int f = fc * FFC + wf * 32 + ftl * 16 + l15;
          aW[ftl] = *reinterpret_cast<const short8*>(W1e + (size_t)f * NC + k);
        }
        __builtin_amdgcn_s_setprio(1);
#pragma unroll
        for (int ftl = 0; ftl < 2; ftl++)
#pragma unroll
          for (int nt = 0; nt < 4; nt++)
            acc1[ftl][nt] = __builtin_amdgcn_mfma_f32_16x16x32_bf16(
                aW[ftl], bX[nt], acc1[ftl][nt], 0, 0, 0);
        __builtin_amdgcn_s_setprio(0);
      }

      // bias + gelu + router-weight scale -> hreg
#pragma unroll
      for (int ftl = 0; ftl < 2; ftl++) {
        int f0 = wf * 32 + ftl * 16 + (lane >> 4) * 4;
        float4 bv = *reinterpret_cast<const float4*>(b1e + fc * FFC + f0);
#pragma unroll
        for (int nt = 0; nt < 4; nt++) {
          float w = (j < 8) ? wvA[nt] : wvB[nt];
          ushort4 hp;
          hp.x = f2b(gelu_f(acc1[ftl][nt][0] + bv.x) * w);
          hp.y = f2b(gelu_f(acc1[ftl][nt][1] + bv.y) * w);
          hp.z = f2b(gelu_f(acc1[ftl][nt][2] + bv.z) * w);
          hp.w = f2b(gelu_f(acc1[ftl][nt][3] + bv.w) * w);
          hreg[ftl * 4 + nt] = hp;
        }
      }
      unsigned short* Hb = &Hl[j & 1][0];
#pragma unroll
      for (int g = 0; g < 8; ++g) {
        int ftl = g >> 2, nt = g & 3;
        int token = nt * 16 + l15;
        int f0 = wf * 32 + ftl * 16 + (lane >> 4) * 4;
        int boff = (token * 256 + f0 * 2) ^ ((token & 7) << 4);
        *reinterpret_cast<ushort4*>((char*)Hb + boff) = hreg[g];
      }
      bar_lgkm();   // chunk j published; G2 done with Hl[j&1]'s previous tenant
    }
    // G1: 16 barriers
  } else {
    // ================= G2: consumer =================
    int wc = wid - 4;
    const unsigned short* W2A = W2b + (size_t)e1 * NC * NFF;
    const unsigned short* W2B = W2b + (size_t)e2 * NC * NFF;

    f32x4 acc2[4][4];   // [ct][rt]
#pragma unroll
    for (int a = 0; a < 4; a++)
#pragma unroll
      for (int b = 0; b < 4; b++)
#pragma unroll
        for (int q = 0; q < 4; q++) acc2[a][b][q] = 0.f;

    bar_lgkm();   // wait for chunk 0

#pragma unroll 1
    for (int j = 0; j < NCHUNK_TOT; ++j) {
      const unsigned short* W2e = (j < 8) ? W2A : W2B;
      int fcp = j & 7;
      const unsigned short* Hb = &Hl[j & 1][0];
#pragma unroll
      for (int ks = 0; ks < 4; ++ks) {        // K = FFC = 128
        int kf = ks * 32 + kgrp;
        short8 aH[4];
#pragma unroll
        for (int rt = 0; rt < 4; rt++) {
          int row = rt * 16 + l15;
          int boff = (row * 256 + kf * 2) ^ ((row & 7) << 4);
          aH[rt] = *reinterpret_cast<const short8*>((const char*)Hb + boff);
        }
        short8 bW[4];
#pragma unroll
        for (int ct = 0; ct < 4; ct++) {
          int c = wc * 64 + ct * 16 + l15;
          bW[ct] = *reinterpret_cast<const short8*>(
              W2e + (size_t)c * NFF + fcp * FFC + kf);
        }
        __builtin_amdgcn_s_setprio(1);
#pragma unroll
        for (int ct = 0; ct < 4; ct++)
#pragma unroll
          for (int rt = 0; rt < 4; rt++)
            acc2[ct][rt] = __builtin_amdgcn_mfma_f32_16x16x32_bf16(
                aH[rt], bW[ct], acc2[ct][rt], 0, 0, 0);
        __builtin_amdgcn_s_setprio(0);
      }
      if (j < NCHUNK_TOT - 1) bar_lgkm();   // total G2 barriers: 1 + 15 = 16
    }

    // ---- epilogue: out = acc2 + wA*b2[e1] + wB*b2[e2] ----
    float b2A4[4], b2B4[4];
#pragma unroll
    for (int ct = 0; ct < 4; ct++) {
      int c = wc * 64 + ct * 16 + l15;
      b2A4[ct] = b2[e1 * NC + c];
      b2B4[ct] = b2[e2 * NC + c];
    }
#pragma unroll
    for (int rt = 0; rt < 4; rt++) {
      if (pbase + rt >= n) continue;
      int pid = pl[rt];
      float wA = wvA[rt], wB = wvB[rt];
      int b = pid >> 10, pi = pid & 1023;
      int phi = pi >> 5, pwi = pi & 31;
#pragma unroll
      for (int i2 = 0; i2 < 4; i2++) {
        int t = (lane >> 4) * 4 + i2;   // token within patch
        float* dst =
            out + (((size_t)(b * NH + phi * 4 + (t >> 2)) * NW) + pwi * 4 + (t & 3)) * NC;
#pragma unroll
        for (int ct = 0; ct < 4; ct++) {
          int c = wc * 64 + ct * 16 + l15;
          dst[c] = acc2[ct][rt][i2] + wA * b2A4[ct] + wB * b2B4[ct];
        }
      }
    }
  }
}

extern "C" void kernel_launch(void* const* d_in, const int* in_sizes, int n_in,
                              void* d_out, int out_size, void* d_ws, size_t ws_size,
                              hipStream_t stream) {
  const float* x  = (const float*)d_in[0];
  const float* Wg = (const float*)d_in[1];
  const float* W1 = (const float*)d_in[2];
  const float* b1 = (const float*)d_in[3];
  const float* W2 = (const float*)d_in[4];
  const float* b2 = (const float*)d_in[5];
  float* out = (float*)d_out;

  char* ws = (char*)d_ws;
  unsigned short* W1b = (unsigned short*)ws;                                  // 2 MiB
  unsigned short* W2b = (unsigned short*)(ws + (size_t)2 * 1024 * 1024);      // 2 MiB
  int*    cnt   = (int*)(ws + (size_t)4 * 1024 * 1024);                       // 64 B
  int*    plist = (int*)(ws + (size_t)4 * 1024 * 1024 + 256);                 // 256 KiB
  float2* wlist = (float2*)(ws + (size_t)4 * 1024 * 1024 + 256 +
                            (size_t)NPAIR * NPATCH * sizeof(int));            // 512 KiB
  int*    wl    = (int*)(ws + (size_t)5 * 1024 * 1024);                       // ~33 KiB

  convert_kernel<<<dim3(4096), dim3(256), 0, stream>>>(W1, W2, W1b, W2b, cnt, NE * NFF * NC);
  router_kernel<<<dim3(NPATCH), dim3(256), 0, stream>>>(x, Wg, cnt, plist, wlist);
  worklist_kernel<<<dim3(1), dim3(64), 0, stream>>>(cnt, wl);

  // padded slots: 8 * max-class-tiles <= 8 * (1024 + 2) = 8208
  ffn_kernel<<<dim3(8208), dim3(512), 0, stream>>>(
      x, b1, b2, W1b, W2b, cnt, plist, wlist, wl, out);
}